// Round 1
// baseline (3000.548 us; speedup 1.0000x reference)
//
#include <hip/hip_runtime.h>
#include <math.h>

// Problem constants
constexpr int NU = 100000;   // users
constexpr int NI = 50000;    // items
constexpr int NN = 150000;   // nodes
constexpr int NE = 1000000;  // edges (directed: 2*NE)
constexpr int D  = 128;

// ---------------- graph build ----------------

__global__ void k_zero(int* __restrict__ p, int n) {
    int i = blockIdx.x * 256 + threadIdx.x;
    if (i < n) p[i] = 0;
}

__global__ void k_degree(const int* __restrict__ ei, int* __restrict__ deg) {
    int e = blockIdx.x * 256 + threadIdx.x;
    if (e < NE) {
        atomicAdd(&deg[ei[e]], 1);
        atomicAdd(&deg[ei[NE + e]], 1);
    }
}

__global__ void k_scan1(const int* __restrict__ deg, int* __restrict__ excl,
                        int* __restrict__ bsums) {
    __shared__ int s[256];
    int tid = threadIdx.x, i = blockIdx.x * 256 + tid;
    int v = (i < NN) ? deg[i] : 0;
    s[tid] = v; __syncthreads();
    for (int off = 1; off < 256; off <<= 1) {
        int t = (tid >= off) ? s[tid - off] : 0;
        __syncthreads();
        s[tid] += t;
        __syncthreads();
    }
    if (i < NN) excl[i] = s[tid] - v;
    if (tid == 255) bsums[blockIdx.x] = s[255];
}

__global__ void k_scan2(const int* __restrict__ bsums, int* __restrict__ bbase, int nb) {
    __shared__ int s[1024];
    int i = threadIdx.x;
    int v = (i < nb) ? bsums[i] : 0;
    s[i] = v; __syncthreads();
    for (int off = 1; off < 1024; off <<= 1) {
        int t = (i >= off) ? s[i - off] : 0;
        __syncthreads();
        s[i] += t;
        __syncthreads();
    }
    bbase[i] = s[i] - v;
}

__global__ void k_scan3(const int* __restrict__ deg, int* __restrict__ rowptr,
                        const int* __restrict__ bbase, int* __restrict__ cursor,
                        float* __restrict__ dis) {
    int i = blockIdx.x * 256 + threadIdx.x;
    if (i < NN) {
        int rp = rowptr[i] + bbase[blockIdx.x];
        rowptr[i] = rp;
        cursor[i] = rp;
        int d = deg[i];
        dis[i] = (d > 0) ? rsqrtf((float)d) : 0.f;
    }
    if (i == 0) rowptr[NN] = 2 * NE;
}

__global__ void k_fill(const int* __restrict__ ei, int* __restrict__ cursor,
                       int* __restrict__ colidx) {
    int e = blockIdx.x * 256 + threadIdx.x;
    if (e < NE) {
        int r = ei[e], c = ei[NE + e];
        colidx[atomicAdd(&cursor[r], 1)] = c;
        colidx[atomicAdd(&cursor[c], 1)] = r;
    }
}

// ---------------- embedding init / propagation ----------------

__global__ void k_init_emb(const float4* __restrict__ ue, const float4* __restrict__ ie,
                           float4* __restrict__ emb0, float4* __restrict__ uacc) {
    int i = blockIdx.x * 256 + threadIdx.x;  // float4 index, NN*32 total
    if (i < NN * 32) {
        float4 v = (i < NU * 32) ? ue[i] : ie[i - NU * 32];
        emb0[i] = v;
        if (i < NU * 32) uacc[i] = v;
    }
}

// one wave (64 lanes) per node; lane handles 2 dims (float2)
__global__ void k_prop(const float* __restrict__ in, float* __restrict__ out,
                       const int* __restrict__ rowptr, const int* __restrict__ colidx,
                       const float* __restrict__ dis, float* __restrict__ uacc) {
    int node = (blockIdx.x * blockDim.x + threadIdx.x) >> 6;
    int lane = threadIdx.x & 63;
    if (node >= NN) return;
    int s = rowptr[node], e = rowptr[node + 1];
    int d0 = lane * 2;
    float ax = 0.f, ay = 0.f;
    for (int j = s; j < e; ++j) {
        int c = colidx[j];
        float w = dis[c];
        float2 v = *(const float2*)(in + (size_t)c * D + d0);
        ax = fmaf(w, v.x, ax);
        ay = fmaf(w, v.y, ay);
    }
    float wn = dis[node];
    ax *= wn; ay *= wn;
    *(float2*)(out + (size_t)node * D + d0) = make_float2(ax, ay);
    if (node < NU) {
        float2* up = (float2*)(uacc + (size_t)node * D + d0);
        float2 t = *up;
        *up = make_float2(t.x + ax, t.y + ay);
    }
}

__global__ void k_scale(float4* __restrict__ p, int n4, float sc) {
    int i = blockIdx.x * 256 + threadIdx.x;
    if (i < n4) {
        float4 v = p[i];
        p[i] = make_float4(v.x * sc, v.y * sc, v.z * sc, v.w * sc);
    }
}

// ---------------- MLP heads ----------------

// C[M,N] = act(A[M,128] @ B[128,N] + bias[N]); ACT 0=relu 1=sigmoid
// 64x64 tile, 256 threads, 4x4 per thread, K=128 fully staged in LDS.
template <int ACT>
__global__ __launch_bounds__(256) void k_gemm128(
    const float* __restrict__ A, const float* __restrict__ B,
    const float* __restrict__ bias, float* __restrict__ C, int M, int N) {
    __shared__ float As[128][64];  // [k][m] (transposed A tile)
    __shared__ float Bs[128][64];  // [k][n]
    const int t = threadIdx.x;
    const int m0 = blockIdx.x * 64;
    const int n0 = blockIdx.y * 64;
    {
        int row = t & 63;
        int k0 = (t >> 6) * 4;
        const float* ap = A + (size_t)(m0 + row) * 128;
        bool okr = (m0 + row) < M;
#pragma unroll
        for (int it = 0; it < 8; ++it) {
            int kk = k0 + it * 16;
            float4 v = okr ? *(const float4*)(ap + kk) : make_float4(0, 0, 0, 0);
            As[kk + 0][row] = v.x;
            As[kk + 1][row] = v.y;
            As[kk + 2][row] = v.z;
            As[kk + 3][row] = v.w;
        }
    }
    {
        int k = t >> 4;
        int n4 = (t & 15) * 4;
        int gn = n0 + n4;
        bool okn = (gn + 3) < N;  // N%4==0 for all our uses -> all-or-nothing
#pragma unroll
        for (int it = 0; it < 8; ++it) {
            int kk = k + it * 16;
            float4 v = okn ? *(const float4*)(B + (size_t)kk * N + gn) : make_float4(0, 0, 0, 0);
            *(float4*)&Bs[kk][n4] = v;
        }
    }
    __syncthreads();
    const int tm = (t >> 4) * 4;
    const int tn = (t & 15) * 4;
    float acc[4][4] = {};
#pragma unroll 4
    for (int k = 0; k < 128; ++k) {
        const float4 av = *(const float4*)&As[k][tm];
        const float4 bv = *(const float4*)&Bs[k][tn];
        const float a0 = av.x, a1 = av.y, a2 = av.z, a3 = av.w;
        const float b0 = bv.x, b1 = bv.y, b2 = bv.z, b3 = bv.w;
        acc[0][0] = fmaf(a0, b0, acc[0][0]); acc[0][1] = fmaf(a0, b1, acc[0][1]);
        acc[0][2] = fmaf(a0, b2, acc[0][2]); acc[0][3] = fmaf(a0, b3, acc[0][3]);
        acc[1][0] = fmaf(a1, b0, acc[1][0]); acc[1][1] = fmaf(a1, b1, acc[1][1]);
        acc[1][2] = fmaf(a1, b2, acc[1][2]); acc[1][3] = fmaf(a1, b3, acc[1][3]);
        acc[2][0] = fmaf(a2, b0, acc[2][0]); acc[2][1] = fmaf(a2, b1, acc[2][1]);
        acc[2][2] = fmaf(a2, b2, acc[2][2]); acc[2][3] = fmaf(a2, b3, acc[2][3]);
        acc[3][0] = fmaf(a3, b0, acc[3][0]); acc[3][1] = fmaf(a3, b1, acc[3][1]);
        acc[3][2] = fmaf(a3, b2, acc[3][2]); acc[3][3] = fmaf(a3, b3, acc[3][3]);
    }
    int colg = n0 + tn;
    if (colg < N) {
        float4 bz = *(const float4*)(bias + colg);
#pragma unroll
        for (int i = 0; i < 4; ++i) {
            int row = m0 + tm + i;
            if (row < M) {
                float z0 = acc[i][0] + bz.x, z1 = acc[i][1] + bz.y;
                float z2 = acc[i][2] + bz.z, z3 = acc[i][3] + bz.w;
                float4 r;
                if (ACT == 0) {
                    r.x = fmaxf(z0, 0.f); r.y = fmaxf(z1, 0.f);
                    r.z = fmaxf(z2, 0.f); r.w = fmaxf(z3, 0.f);
                } else {
                    r.x = 1.f / (1.f + __expf(-z0));
                    r.y = 1.f / (1.f + __expf(-z1));
                    r.z = 1.f / (1.f + __expf(-z2));
                    r.w = 1.f / (1.f + __expf(-z3));
                }
                *(float4*)(C + (size_t)row * N + colg) = r;
            }
        }
    }
}

// churn head output: one wave per row, dot(h_row[128], w2[128]) -> sigmoid
__global__ void k_churn(const float* __restrict__ h, const float* __restrict__ w2,
                        const float* __restrict__ b2, float* __restrict__ out) {
    int gw = (blockIdx.x * blockDim.x + threadIdx.x) >> 6;
    int lane = threadIdx.x & 63;
    if (gw >= NU) return;
    float2 hv = *(const float2*)(h + (size_t)gw * 128 + lane * 2);
    float2 wv = *(const float2*)(w2 + lane * 2);
    float s = hv.x * wv.x + hv.y * wv.y;
#pragma unroll
    for (int off = 32; off > 0; off >>= 1) s += __shfl_xor(s, off, 64);
    if (lane == 0) out[gw] = 1.f / (1.f + __expf(-(s + b2[0])));
}

// ---------------- launch ----------------

extern "C" void kernel_launch(void* const* d_in, const int* in_sizes, int n_in,
                              void* d_out, int out_size, void* d_ws, size_t ws_size,
                              hipStream_t stream) {
    const int*   ei  = (const int*)d_in[0];
    const float* ue  = (const float*)d_in[1];
    const float* ie  = (const float*)d_in[2];
    const float* cw1 = (const float*)d_in[3];
    const float* cb1 = (const float*)d_in[4];
    const float* cw2 = (const float*)d_in[5];
    const float* cb2 = (const float*)d_in[6];
    const float* aw1 = (const float*)d_in[7];
    const float* ab1 = (const float*)d_in[8];
    const float* aw2 = (const float*)d_in[9];
    const float* ab2 = (const float*)d_in[10];
    const float* sw1 = (const float*)d_in[11];
    const float* sb1 = (const float*)d_in[12];
    const float* sw2 = (const float*)d_in[13];
    const float* sb2 = (const float*)d_in[14];

    float* out = (float*)d_out;
    float* out_churn = out;                  // [100000,1]
    float* out_cat   = out + 100000;         // [100000,100]
    float* out_sku   = out + 10100000;       // [100000,2000]
    float* out_u     = out + 210100000;      // [100000,128]

    // workspace layout (ints/floats), ~62 MB total
    int*   deg    = (int*)d_ws;
    int*   rowptr = deg + 150016;     // needs 150001
    int*   cursor = rowptr + 150016;
    int*   bsums  = cursor + 150016;  // 1024
    int*   bbase  = bsums + 1024;     // 1024
    float* dis    = (float*)(bbase + 1024);      // 150016
    int*   colidx = (int*)(dis + 150016);        // 2,000,000
    float* h      = (float*)(colidx + 2000000);  // 12,800,000

    // big embedding ping-pong buffers live in the (dead until last) sku region
    float* emb0 = out_sku;             // 19,200,000 floats
    float* emb1 = out_sku + 19200000;  // 19,200,000 floats

    int nb = (NN + 255) / 256;  // 586

    k_zero<<<586, 256, 0, stream>>>(deg, 150016);
    k_degree<<<(NE + 255) / 256, 256, 0, stream>>>(ei, deg);
    k_scan1<<<nb, 256, 0, stream>>>(deg, rowptr, bsums);
    k_scan2<<<1, 1024, 0, stream>>>(bsums, bbase, nb);
    k_scan3<<<nb, 256, 0, stream>>>(deg, rowptr, bbase, cursor, dis);
    k_fill<<<(NE + 255) / 256, 256, 0, stream>>>(ei, cursor, colidx);

    k_init_emb<<<(NN * 32) / 256, 256, 0, stream>>>(
        (const float4*)ue, (const float4*)ie, (float4*)emb0, (float4*)out_u);

    k_prop<<<NN / 4, 256, 0, stream>>>(emb0, emb1, rowptr, colidx, dis, out_u);
    k_prop<<<NN / 4, 256, 0, stream>>>(emb1, emb0, rowptr, colidx, dis, out_u);
    k_prop<<<NN / 4, 256, 0, stream>>>(emb0, emb1, rowptr, colidx, dis, out_u);

    k_scale<<<(NU * 32) / 256, 256, 0, stream>>>((float4*)out_u, NU * 32, 0.25f);

    dim3 gh((NU + 63) / 64, 2);  // hidden: N=128 -> grid.y=2
    // churn head
    k_gemm128<0><<<gh, 256, 0, stream>>>(out_u, cw1, cb1, h, NU, 128);
    k_churn<<<NU / 4, 256, 0, stream>>>(h, cw2, cb2, out_churn);
    // cat head
    k_gemm128<0><<<gh, 256, 0, stream>>>(out_u, aw1, ab1, h, NU, 128);
    k_gemm128<1><<<dim3((NU + 63) / 64, (100 + 63) / 64), 256, 0, stream>>>(
        h, aw2, ab2, out_cat, NU, 100);
    // sku head (writes the whole sku region, overwriting dead emb0/emb1)
    k_gemm128<0><<<gh, 256, 0, stream>>>(out_u, sw1, sb1, h, NU, 128);
    k_gemm128<1><<<dim3((NU + 63) / 64, (2000 + 63) / 64), 256, 0, stream>>>(
        h, sw2, sb2, out_sku, NU, 2000);
}